// Round 2
// baseline (158.259 us; speedup 1.0000x reference)
//
#include <hip/hip_runtime.h>

// Fused BERT-CRF NER: one block per batch (grid=256, block=256 = 4 waves).
// Per 16-row chunk: 4 waves compute feats rows (X[16,768]@W^T[768,13]+b) into
// LDS (double-buffered X in regs, loads issued one chunk ahead); wave 0 then
// runs 16 Viterbi steps from LDS. Forward pass also composes per-chunk
// ancestor maps so the backtrace is a 15-hop boundary chase + 16 parallel
// 16-step interior chases instead of a 255-step serial LDS pointer chase.
// B=256, T=256, H=768, L=13, START=11.
//
// Outputs (float32, concatenated): [0..255] max_p/T per batch; [256..65791] path.

#define NEGV (-10000.0f)

__device__ __forceinline__ void load_rows(const float* __restrict__ Xb, int chunk,
                                          int wave, int lane, float (&x)[4][12]) {
  const float* base = Xb + (chunk * 16 + wave * 4) * 768 + 4 * lane;
  #pragma unroll
  for (int r = 0; r < 4; ++r) {
    #pragma unroll
    for (int j = 0; j < 3; ++j) {
      float4 v = *reinterpret_cast<const float4*>(base + r * 768 + 256 * j);
      x[r][4 * j + 0] = v.x; x[r][4 * j + 1] = v.y;
      x[r][4 * j + 2] = v.z; x[r][4 * j + 3] = v.w;
    }
  }
}

// Identical math to the passing round-1 feats kernel: per-lane 12-elem k-slice,
// sequential FMAs, full 64-lane xor butterfly, lane<13 writes row outputs.
__device__ __forceinline__ void gemm_store(const float (&x)[4][12], int chunk,
                                           int wave, int lane,
                                           const float* Ws, const float* Bs,
                                           float* fs) {
  float acc[4][13];
  #pragma unroll
  for (int r = 0; r < 4; ++r)
    #pragma unroll
    for (int cc = 0; cc < 13; ++cc) acc[r][cc] = 0.0f;

  #pragma unroll
  for (int col = 0; col < 13; ++col) {
    float w[12];
    const float* wp = Ws + col * 768 + 4 * lane;
    #pragma unroll
    for (int j = 0; j < 3; ++j) {
      float4 v = *reinterpret_cast<const float4*>(wp + 256 * j);
      w[4 * j + 0] = v.x; w[4 * j + 1] = v.y;
      w[4 * j + 2] = v.z; w[4 * j + 3] = v.w;
    }
    #pragma unroll
    for (int r = 0; r < 4; ++r)
      #pragma unroll
      for (int k = 0; k < 12; ++k)
        acc[r][col] = fmaf(x[r][k], w[k], acc[r][col]);
  }

  #pragma unroll
  for (int r = 0; r < 4; ++r) {
    #pragma unroll
    for (int cc = 0; cc < 13; ++cc) {
      float v = acc[r][cc];
      v += __shfl_xor(v, 1);
      v += __shfl_xor(v, 2);
      v += __shfl_xor(v, 4);
      v += __shfl_xor(v, 8);
      v += __shfl_xor(v, 16);
      v += __shfl_xor(v, 32);
      acc[r][cc] = v;
    }
    float v = acc[r][0];
    #pragma unroll
    for (int cc = 1; cc < 13; ++cc) v = (lane == cc) ? acc[r][cc] : v;
    v += Bs[lane & 15];
    int row = chunk * 16 + wave * 4 + r;
    if (lane < 13) fs[row * 13 + lane] = v;
  }
}

// 16 (15 for chunk 0) Viterbi steps; instruction-identical recurrence to the
// passing round-1 kernel. Also composes the chunk's ancestor map into Mm.
__device__ __forceinline__ void vit_chunk(int chunk, int lane,
                                          const float (&tr)[13], float& ld,
                                          const float* fs, unsigned char* psi,
                                          unsigned char* Mm) {
  const int t0 = (chunk == 0) ? 1 : chunk * 16;
  const int t1 = chunk * 16 + 15;
  int anc = lane;
  for (int t = t0; t <= t1; ++t) {
    float ft = fs[t * 13 + (lane & 15)];
    float c[13];
    #pragma unroll
    for (int f = 0; f < 13; ++f) {
      float lf = __uint_as_float(
          __builtin_amdgcn_readlane(__float_as_uint(ld), f));
      c[f] = tr[f] + lf;
    }
    float m0 = fmaxf(fmaxf(c[0], c[1]), c[2]);
    float m1 = fmaxf(fmaxf(c[3], c[4]), c[5]);
    float m2 = fmaxf(fmaxf(c[6], c[7]), c[8]);
    float m3 = fmaxf(fmaxf(c[9], c[10]), c[11]);
    float m  = fmaxf(fmaxf(fmaxf(m0, m1), fmaxf(m2, m3)), c[12]);

    int idx = 0;
    #pragma unroll
    for (int f = 12; f >= 0; --f)
      idx = (c[f] == m) ? f : idx;   // first index wins on ties

    if (lane < 16) psi[t * 16 + lane] = (unsigned char)idx;
    anc = __shfl(anc, idx);          // ancestor-at-chunk-entry composition
    ld = m + ft;
  }
  if (lane < 13) Mm[chunk * 16 + lane] = (unsigned char)anc;
}

__global__ __launch_bounds__(256) void fused_kernel(
    const float* __restrict__ X,      // [256,256,768]
    const float* __restrict__ W,      // [13,768]
    const float* __restrict__ bias,   // [13]
    const float* __restrict__ trans,  // [13,13]
    float* __restrict__ out)          // [256 + 65536]
{
  __shared__ float Ws[13 * 768];          // 39936 B
  __shared__ float Bs[16];
  __shared__ float fs[3344];              // feats [256][13] (+pad)
  __shared__ unsigned char psi[4096];     // [256][16]
  __shared__ unsigned char Mm[256];       // [16 chunks][16]
  __shared__ unsigned char bnd[16];
  __shared__ unsigned char path[256];
  __shared__ float ldf[13];

  const int tid = threadIdx.x;
  const int wave = tid >> 6, lane = tid & 63;
  const int b = blockIdx.x;

  {  // stage W + bias
    const float4* Wv = reinterpret_cast<const float4*>(W);
    float4* Wsv = reinterpret_cast<float4*>(Ws);
    #pragma unroll
    for (int j = 0; j < 10; ++j) {
      int i = tid + j * 256;
      if (i < 2496) Wsv[i] = Wv[i];
    }
    if (tid < 13) Bs[tid] = bias[tid];
    if (tid >= 13 && tid < 16) Bs[tid] = 0.0f;
  }

  float tr[13];
  #pragma unroll
  for (int f = 0; f < 13; ++f)
    tr[f] = (wave == 0 && lane < 13) ? trans[lane * 13 + f] : -1.0e30f;

  __syncthreads();

  const float* Xb = X + (long)b * (256 * 768);
  float xA[4][12], xB[4][12];
  load_rows(Xb, 0, wave, lane, xA);

  float ld = (lane == 11) ? 0.0f : NEGV;  // START = 11

  for (int c = 0; c < 16; c += 2) {
    load_rows(Xb, c + 1, wave, lane, xB);         // prefetch next chunk
    gemm_store(xA, c, wave, lane, Ws, Bs, fs);
    __syncthreads();
    if (wave == 0) vit_chunk(c, lane, tr, ld, fs, psi, Mm);

    if (c + 2 < 16) load_rows(Xb, c + 2, wave, lane, xA);
    gemm_store(xB, c + 1, wave, lane, Ws, Bs, fs);
    __syncthreads();
    if (wave == 0) vit_chunk(c + 1, lane, tr, ld, fs, psi, Mm);
  }

  if (wave == 0 && lane < 13) ldf[lane] = ld;
  __syncthreads();

  if (tid == 0) {
    float m = ldf[0];
    int last = 0;
    #pragma unroll
    for (int i = 1; i < 13; ++i)
      if (ldf[i] > m) { m = ldf[i]; last = i; }   // strict >: first index
    float s = 0.0f;
    #pragma unroll
    for (int i = 0; i < 13; ++i) s += expf(ldf[i] - m);
    out[b] = 1.0f / (256.0f * s);                 // max(softmax)/T

    int cur = last;
    bnd[15] = (unsigned char)cur;
    #pragma unroll
    for (int cc = 15; cc >= 1; --cc) {            // boundary chase over maps
      cur = Mm[cc * 16 + cur];
      bnd[cc - 1] = (unsigned char)cur;
    }
  }
  __syncthreads();

  if (tid < 16) {  // 16 parallel interior chases (one lane per chunk)
    int cur = bnd[tid];
    const int tHi = tid * 16 + 15;
    path[tHi] = (unsigned char)cur;
    const int tLo = (tid == 0) ? 1 : tid * 16;
    for (int t = tHi; t >= tLo; --t) {
      cur = psi[t * 16 + cur];
      path[t - 1] = (unsigned char)cur;
    }
  }
  __syncthreads();

  out[256 + (long)b * 256 + tid] = (float)path[tid];
}

// ------------------------------------------------------------------ launch --
extern "C" void kernel_launch(void* const* d_in, const int* in_sizes, int n_in,
                              void* d_out, int out_size, void* d_ws, size_t ws_size,
                              hipStream_t stream) {
  const float* X     = (const float*)d_in[0];
  const float* W     = (const float*)d_in[1];
  const float* bias  = (const float*)d_in[2];
  const float* trans = (const float*)d_in[3];
  float* out = (float*)d_out;

  fused_kernel<<<256, 256, 0, stream>>>(X, W, bias, trans, out);
}

// Round 3
// 138.429 us; speedup vs baseline: 1.1433x; 1.1433x over previous
//
#include <hip/hip_runtime.h>

// BERT-CRF NER, two kernels:
//  K1 feats: X[65536,768] @ W^T[768,13] + b -> featsT[13][65536] (transposed,
//     coalesced stores). lane=row, 13 regs/lane, NO cross-lane reduction.
//     X staged via global_load_lds into XOR-swizzled LDS tiles, triple-buffered
//     with counted vmcnt; W broadcast from LDS.
//  K2 viterbi: one wave per batch, round-1 recurrence + ancestor-map backtrace.
// B=256, T=256, H=768, L=13, START=11.
// Outputs (float32): [0..255] max_p/T; [256..65791] path.

#define NEGV (-10000.0f)

typedef __attribute__((address_space(1))) const void  gvoid;
typedef __attribute__((address_space(3))) void        svoid;

__device__ __forceinline__ void gload_lds16(const float* g, float* lds) {
  __builtin_amdgcn_global_load_lds((gvoid*)g, (svoid*)lds, 16, 0, 0);
}

// ---------------------------------------------------------------- kernel 1 --
// Block: 256 threads (4 waves) = 256 rows. 24 k-chunks of 32. LDS: W 39 KB +
// 3 x 32 KB X tiles = 135 KB -> 1 block/CU by design.
// LDS tile layout: Xs[buf][row][slot], slot s holds k-group (s ^ (row&7))
// (XOR swizzle applied on the global SOURCE address; involution on read).
__global__ __launch_bounds__(256) void feats_kernel(
    const float* __restrict__ X,      // [65536, 768]
    const float* __restrict__ W,      // [13, 768]
    const float* __restrict__ bias,   // [13]
    float* __restrict__ featsT)       // [13][65536]
{
  __shared__ float Ws[13 * 768];
  __shared__ float Bs[16];
  __shared__ float Xs[3][256 * 32];   // 3 x 32 KB

  const int tid = threadIdx.x;
  const int w = tid >> 6, l = tid & 63;
  const int b = blockIdx.x;

  {  // stage W + bias (before any chunk DMA so vmcnt bookkeeping stays clean)
    const float4* Wv = reinterpret_cast<const float4*>(W);
    float4* Wsv = reinterpret_cast<float4*>(Ws);
    #pragma unroll
    for (int j = 0; j < 10; ++j) {
      int i = tid + j * 256;
      if (i < 2496) Wsv[i] = Wv[i];
    }
    if (tid < 13) Bs[tid] = bias[tid];
    if (tid >= 13 && tid < 16) Bs[tid] = 0.0f;
  }
  __syncthreads();   // also drains vmcnt before the DMA loop

  const float* Xb = X + (long)b * 196608;   // this block's 256 rows
  const int r0 = l >> 3;                    // row-within-8 this lane stages
  const int slot = l & 7;
  const int ksw = ((slot ^ r0) << 2);       // swizzled k offset (indep. of i)
  const int l7 = l & 7;                     // == rowL & 7 for compute

  // stage chunk c into buffer bi: wave w stages ONLY its own rows
  // (w*64 .. w*64+63) -> no inter-wave barrier needed in the main loop.
  #define STAGE(c, bi)                                                        \
    {                                                                         \
      const int kbase = (c) * 32;                                             \
      _Pragma("unroll")                                                       \
      for (int i = 0; i < 8; ++i) {                                           \
        const float* src = Xb + (w * 64 + i * 8 + r0) * 768 + kbase + ksw;    \
        float* dst = &Xs[bi][(w * 64 + i * 8) * 32];                          \
        gload_lds16(src, dst);                                                \
      }                                                                       \
    }

  STAGE(0, 0)
  STAGE(1, 1)
  STAGE(2, 2)

  float acc[13];
  #pragma unroll
  for (int c = 0; c < 13; ++c) acc[c] = 0.0f;

  const int rowL = w * 64 + l;

  #pragma unroll 1
  for (int c = 0; c < 24; ++c) {
    if (c < 22)       asm volatile("s_waitcnt vmcnt(16)" ::: "memory");
    else if (c == 22) asm volatile("s_waitcnt vmcnt(8)"  ::: "memory");
    else              asm volatile("s_waitcnt vmcnt(0)"  ::: "memory");

    const float* xrow = &Xs[c % 3][rowL * 32];
    const float* wbase = Ws + c * 32;
    #pragma unroll
    for (int j = 0; j < 8; ++j) {
      float4 x = *reinterpret_cast<const float4*>(xrow + ((j ^ l7) << 2));
      #pragma unroll
      for (int col = 0; col < 13; ++col) {
        float4 wv = *reinterpret_cast<const float4*>(wbase + col * 768 + j * 4);
        acc[col] = fmaf(x.x, wv.x, acc[col]);
        acc[col] = fmaf(x.y, wv.y, acc[col]);
        acc[col] = fmaf(x.z, wv.z, acc[col]);
        acc[col] = fmaf(x.w, wv.w, acc[col]);
      }
    }
    // ensure this buffer's LDS reads completed before its DMA overwrite below
    asm volatile("s_waitcnt lgkmcnt(0)" ::: "memory");
    if (c + 3 < 24) STAGE(c + 3, (c + 3) % 3)
  }
  #undef STAGE

  // bias + transposed coalesced store: featsT[col][b*256 + rowL]
  const long rowG = (long)b * 256 + rowL;
  #pragma unroll
  for (int col = 0; col < 13; ++col)
    featsT[(long)col * 65536 + rowG] = acc[col] + Bs[col];
}

// ---------------------------------------------------------------- kernel 2 --
// One wave per batch. Forward recurrence identical to the passing round-1
// kernel; adds per-16-step ancestor-map composition (one __shfl per step, off
// the ld critical chain) so the backtrace is a 15-hop boundary chase plus 16
// parallel 16-step interior chases.
__global__ __launch_bounds__(64) void viterbi_kernel(
    const float* __restrict__ featsT,  // [13][65536]
    const float* __restrict__ trans,   // [13,13]
    float* __restrict__ out)           // [256 + 65536]
{
  __shared__ float fs[3344];               // feats[t][c], 256*13 used (+pad)
  __shared__ unsigned char psi[256 * 16];
  __shared__ unsigned char Mm[256];        // [16 chunks][16]
  __shared__ unsigned char bnd[16];
  __shared__ unsigned char path[256];
  __shared__ float ldf[13];

  const int b = blockIdx.x;
  const int lane = threadIdx.x;

  // stage this batch's feats from the transposed layout: col i, t = 4*lane..+3
  #pragma unroll
  for (int i = 0; i < 13; ++i) {
    float4 v = *reinterpret_cast<const float4*>(
        featsT + (long)i * 65536 + b * 256 + 4 * lane);
    fs[(4 * lane + 0) * 13 + i] = v.x;
    fs[(4 * lane + 1) * 13 + i] = v.y;
    fs[(4 * lane + 2) * 13 + i] = v.z;
    fs[(4 * lane + 3) * 13 + i] = v.w;
  }
  __syncthreads();

  float tr[13];
  #pragma unroll
  for (int f = 0; f < 13; ++f)
    tr[f] = (lane < 13) ? trans[lane * 13 + f] : -1.0e30f;

  float ld = (lane == 11) ? 0.0f : NEGV;  // START = 11
  int anc = lane;

  for (int t = 1; t < 256; ++t) {
    float c[13];
    #pragma unroll
    for (int f = 0; f < 13; ++f) {
      float lf = __uint_as_float(
          __builtin_amdgcn_readlane(__float_as_uint(ld), f));
      c[f] = tr[f] + lf;
    }
    float m0 = fmaxf(fmaxf(c[0], c[1]), c[2]);
    float m1 = fmaxf(fmaxf(c[3], c[4]), c[5]);
    float m2 = fmaxf(fmaxf(c[6], c[7]), c[8]);
    float m3 = fmaxf(fmaxf(c[9], c[10]), c[11]);
    float m  = fmaxf(fmaxf(fmaxf(m0, m1), fmaxf(m2, m3)), c[12]);

    int idx = 0;
    #pragma unroll
    for (int f = 12; f >= 0; --f)
      idx = (c[f] == m) ? f : idx;        // first index wins on ties

    float ft = fs[t * 13 + (lane & 15)];
    if (lane < 16) psi[t * 16 + lane] = (unsigned char)idx;
    anc = __shfl(anc, idx);               // ancestor composition (off-chain)
    ld = m + ft;

    if ((t & 15) == 15) {                 // chunk boundary: store map, reset
      if (lane < 13) Mm[(t >> 4) * 16 + lane] = (unsigned char)anc;
      anc = lane;
    }
  }

  __syncthreads();
  if (lane < 13) ldf[lane] = ld;
  __syncthreads();

  if (lane == 0) {
    float m = ldf[0]; int last = 0;
    #pragma unroll
    for (int i = 1; i < 13; ++i)
      if (ldf[i] > m) { m = ldf[i]; last = i; }   // strict >: first index
    float s = 0.0f;
    #pragma unroll
    for (int i = 0; i < 13; ++i) s += expf(ldf[i] - m);
    out[b] = 1.0f / (256.0f * s);                 // max(softmax)/T

    int cur = last;
    bnd[15] = (unsigned char)cur;
    #pragma unroll
    for (int cc = 15; cc >= 1; --cc) {            // boundary chase over maps
      cur = Mm[cc * 16 + cur];
      bnd[cc - 1] = (unsigned char)cur;
    }
  }
  __syncthreads();

  if (lane < 16) {  // 16 parallel interior chases (one lane per chunk)
    int cur = bnd[lane];
    const int tHi = lane * 16 + 15;
    path[tHi] = (unsigned char)cur;
    const int tLo = (lane == 0) ? 1 : lane * 16;
    for (int t = tHi; t >= tLo; --t) {
      cur = psi[t * 16 + cur];
      path[t - 1] = (unsigned char)cur;
    }
  }
  __syncthreads();

  float* po = out + 256 + (long)b * 256;
  #pragma unroll
  for (int j = 0; j < 4; ++j)
    po[lane + 64 * j] = (float)path[lane + 64 * j];
}

// ------------------------------------------------------------------ launch --
extern "C" void kernel_launch(void* const* d_in, const int* in_sizes, int n_in,
                              void* d_out, int out_size, void* d_ws, size_t ws_size,
                              hipStream_t stream) {
  const float* X     = (const float*)d_in[0];
  const float* W     = (const float*)d_in[1];
  const float* bias  = (const float*)d_in[2];
  const float* trans = (const float*)d_in[3];
  float* out    = (float*)d_out;
  float* featsT = (float*)d_ws;   // 13*65536 floats = 3.4 MB

  feats_kernel<<<256, 256, 0, stream>>>(X, W, bias, featsT);
  viterbi_kernel<<<256, 64, 0, stream>>>(featsT, trans, out);
}

// Round 4
// 106.803 us; speedup vs baseline: 1.4818x; 1.2961x over previous
//
#include <hip/hip_runtime.h>

// BERT-CRF NER, two kernels.
//  K1 feats (UNCHANGED from round 3, passed absmax 0): X @ W^T + b -> featsT.
//  K2 viterbi (rewritten): value-only serial forward (psi deferred), ft
//     preloaded per 16-step chunk from transposed LDS, psi + ancestor maps
//     computed in parallel phases, then boundary/interior backtrace.
// B=256, T=256, H=768, L=13, START=11.
// Outputs (float32): [0..255] max_p/T; [256..65791] path.

#define NEGV (-10000.0f)

typedef __attribute__((address_space(1))) const void  gvoid;
typedef __attribute__((address_space(3))) void        svoid;

__device__ __forceinline__ void gload_lds16(const float* g, float* lds) {
  __builtin_amdgcn_global_load_lds((gvoid*)g, (svoid*)lds, 16, 0, 0);
}

// ---------------------------------------------------------------- kernel 1 --
// (byte-identical to round 3's passing feats kernel)
__global__ __launch_bounds__(256) void feats_kernel(
    const float* __restrict__ X,      // [65536, 768]
    const float* __restrict__ W,      // [13, 768]
    const float* __restrict__ bias,   // [13]
    float* __restrict__ featsT)       // [13][65536]
{
  __shared__ float Ws[13 * 768];
  __shared__ float Bs[16];
  __shared__ float Xs[3][256 * 32];   // 3 x 32 KB

  const int tid = threadIdx.x;
  const int w = tid >> 6, l = tid & 63;
  const int b = blockIdx.x;

  {
    const float4* Wv = reinterpret_cast<const float4*>(W);
    float4* Wsv = reinterpret_cast<float4*>(Ws);
    #pragma unroll
    for (int j = 0; j < 10; ++j) {
      int i = tid + j * 256;
      if (i < 2496) Wsv[i] = Wv[i];
    }
    if (tid < 13) Bs[tid] = bias[tid];
    if (tid >= 13 && tid < 16) Bs[tid] = 0.0f;
  }
  __syncthreads();

  const float* Xb = X + (long)b * 196608;
  const int r0 = l >> 3;
  const int slot = l & 7;
  const int ksw = ((slot ^ r0) << 2);
  const int l7 = l & 7;

  #define STAGE(c, bi)                                                        \
    {                                                                         \
      const int kbase = (c) * 32;                                             \
      _Pragma("unroll")                                                       \
      for (int i = 0; i < 8; ++i) {                                           \
        const float* src = Xb + (w * 64 + i * 8 + r0) * 768 + kbase + ksw;    \
        float* dst = &Xs[bi][(w * 64 + i * 8) * 32];                          \
        gload_lds16(src, dst);                                                \
      }                                                                       \
    }

  STAGE(0, 0)
  STAGE(1, 1)
  STAGE(2, 2)

  float acc[13];
  #pragma unroll
  for (int c = 0; c < 13; ++c) acc[c] = 0.0f;

  const int rowL = w * 64 + l;

  #pragma unroll 1
  for (int c = 0; c < 24; ++c) {
    if (c < 22)       asm volatile("s_waitcnt vmcnt(16)" ::: "memory");
    else if (c == 22) asm volatile("s_waitcnt vmcnt(8)"  ::: "memory");
    else              asm volatile("s_waitcnt vmcnt(0)"  ::: "memory");

    const float* xrow = &Xs[c % 3][rowL * 32];
    const float* wbase = Ws + c * 32;
    #pragma unroll
    for (int j = 0; j < 8; ++j) {
      float4 x = *reinterpret_cast<const float4*>(xrow + ((j ^ l7) << 2));
      #pragma unroll
      for (int col = 0; col < 13; ++col) {
        float4 wv = *reinterpret_cast<const float4*>(wbase + col * 768 + j * 4);
        acc[col] = fmaf(x.x, wv.x, acc[col]);
        acc[col] = fmaf(x.y, wv.y, acc[col]);
        acc[col] = fmaf(x.z, wv.z, acc[col]);
        acc[col] = fmaf(x.w, wv.w, acc[col]);
      }
    }
    asm volatile("s_waitcnt lgkmcnt(0)" ::: "memory");
    if (c + 3 < 24) STAGE(c + 3, (c + 3) % 3)
  }
  #undef STAGE

  const long rowG = (long)b * 256 + rowL;
  #pragma unroll
  for (int col = 0; col < 13; ++col)
    featsT[(long)col * 65536 + rowG] = acc[col] + Bs[col];
}

// ---------------------------------------------------------------- kernel 2 --
// Block = 256 threads (4 waves) per batch.
// Phase 1 (wave 0, lanes<16): value-only forward, ld_t stored to LDS.
// Phase 2 (all threads): psi[t][to] recomputed in parallel over t.
// Phase 3 (all threads): per-chunk ancestor maps Mm via 16-hop psi chases.
// Phase 4 (tid 0): softmax out + 15-hop boundary chase.
// Phase 5 (tid<16): 16 parallel interior chases; then path writes.
__global__ __launch_bounds__(256) void viterbi_kernel(
    const float* __restrict__ featsT,  // [13][65536]
    const float* __restrict__ trans,   // [13,13]
    float* __restrict__ out)           // [256 + 65536]
{
  __shared__ float fsT[13 * 260];          // feats transposed [to][t] (pad 260)
  __shared__ float lds_ld[256 * 16];       // ld_t[to], t = 0..255
  __shared__ float trL[176];               // trans (169 used)
  __shared__ unsigned char psi[256 * 16];  // psi[t][to]
  __shared__ unsigned char Mm[256];        // [16 chunks][16]
  __shared__ unsigned char bnd[16];
  __shared__ unsigned char path[256];

  const int tid = threadIdx.x;
  const int w = tid >> 6, lane = tid & 63;
  const int b = blockIdx.x;

  // stage feats (transposed rows of this batch) + trans
  #pragma unroll
  for (int i = 0; i < 13; ++i)
    fsT[i * 260 + tid] = featsT[(long)i * 65536 + b * 256 + tid];
  if (tid < 169) trL[tid] = trans[tid];
  __syncthreads();

  // ---- phase 1: serial forward (values only), wave 0, lower half-wave ----
  if (w == 0 && lane < 16) {
    float tr[13];
    #pragma unroll
    for (int f = 0; f < 13; ++f)
      tr[f] = (lane < 13) ? trans[lane * 13 + f] : -1.0e30f;

    const int toc = (lane < 13) ? lane : 0;
    const float* frow = &fsT[toc * 260];

    float ld = (lane == 11) ? 0.0f : NEGV;  // START = 11
    if (lane < 13) lds_ld[lane] = ld;       // t = 0

    float4 F[4], Fn[4];
    #pragma unroll
    for (int q = 0; q < 4; ++q)
      F[q] = *reinterpret_cast<const float4*>(frow + 4 * q);

    #pragma unroll 1
    for (int g = 0; g < 16; ++g) {
      if (g < 15) {
        #pragma unroll
        for (int q = 0; q < 4; ++q)
          Fn[q] = *reinterpret_cast<const float4*>(frow + (g + 1) * 16 + 4 * q);
      }
      const int kLo = (g == 0) ? 1 : 0;     // skip t = 0
      #pragma unroll
      for (int k = 0; k < 16; ++k) {
        if (k < kLo) continue;              // g==0 peel handled by unroll+const
        const int t = g * 16 + k;
        float c[13];
        #pragma unroll
        for (int f = 0; f < 13; ++f) {
          float lf = __uint_as_float(
              __builtin_amdgcn_readlane(__float_as_uint(ld), f));
          c[f] = tr[f] + lf;
        }
        float p0 = fmaxf(fmaxf(c[0], c[1]), c[2]);
        float p1 = fmaxf(fmaxf(c[3], c[4]), c[5]);
        float p2 = fmaxf(fmaxf(c[6], c[7]), c[8]);
        float p3 = fmaxf(fmaxf(c[9], c[10]), c[11]);
        float m  = fmaxf(fmaxf(fmaxf(p0, p1), p2), fmaxf(p3, c[12]));

        const float4 fq = F[k >> 2];
        const float ft = ((k & 3) == 0) ? fq.x : ((k & 3) == 1) ? fq.y
                        : ((k & 3) == 2) ? fq.z : fq.w;
        ld = m + ft;
        if (lane < 13) lds_ld[t * 16 + lane] = ld;
      }
      #pragma unroll
      for (int q = 0; q < 4; ++q) F[q] = Fn[q];
    }
  }
  __syncthreads();

  // ---- phase 2: psi in parallel over t; thread = (to = tid&15, dtt = tid>>4)
  {
    const int to = tid & 15, dtt = tid >> 4;
    if (to < 13) {
      float trr[13];
      #pragma unroll
      for (int f = 0; f < 13; ++f) trr[f] = trL[to * 13 + f];
      for (int t = (dtt == 0 ? 16 : dtt); t < 256; t += 16) {
        const float* lp = &lds_ld[(t - 1) * 16];
        float4 l0 = *reinterpret_cast<const float4*>(lp);
        float4 l1 = *reinterpret_cast<const float4*>(lp + 4);
        float4 l2 = *reinterpret_cast<const float4*>(lp + 8);
        float4 l3 = *reinterpret_cast<const float4*>(lp + 12);
        float c[13] = {trr[0] + l0.x,  trr[1] + l0.y,  trr[2] + l0.z,
                       trr[3] + l0.w,  trr[4] + l1.x,  trr[5] + l1.y,
                       trr[6] + l1.z,  trr[7] + l1.w,  trr[8] + l2.x,
                       trr[9] + l2.y,  trr[10] + l2.z, trr[11] + l2.w,
                       trr[12] + l3.x};
        float best = c[0]; int bf = 0;
        #pragma unroll
        for (int f = 1; f < 13; ++f) {
          bool gt = c[f] > best;              // strict >: first index wins
          best = gt ? c[f] : best;
          bf   = gt ? f : bf;
        }
        psi[t * 16 + to] = (unsigned char)bf;
      }
    }
  }
  __syncthreads();

  // ---- phase 3: ancestor maps, thread = (s = tid&15, g = tid>>4) ----
  {
    const int s = tid & 15, g = tid >> 4;
    if (s < 13) {
      int cur = s;
      const int tLo = (g == 0) ? 1 : g * 16;
      for (int t = g * 16 + 15; t >= tLo; --t)
        cur = psi[t * 16 + cur];
      Mm[g * 16 + s] = (unsigned char)cur;
    }
  }
  __syncthreads();

  // ---- phase 4: softmax output + boundary chase (tid 0) ----
  if (tid == 0) {
    const float* lf = &lds_ld[255 * 16];
    float m = lf[0]; int last = 0;
    #pragma unroll
    for (int i = 1; i < 13; ++i)
      if (lf[i] > m) { m = lf[i]; last = i; }   // strict >: first index
    float s = 0.0f;
    #pragma unroll
    for (int i = 0; i < 13; ++i) s += expf(lf[i] - m);
    out[b] = 1.0f / (256.0f * s);               // max(softmax)/T

    int cur = last;
    bnd[15] = (unsigned char)cur;
    #pragma unroll
    for (int cc = 15; cc >= 1; --cc) {
      cur = Mm[cc * 16 + cur];
      bnd[cc - 1] = (unsigned char)cur;
    }
  }
  __syncthreads();

  // ---- phase 5: interior chases (tid<16, one chunk each) ----
  if (tid < 16) {
    int cur = bnd[tid];
    const int tHi = tid * 16 + 15;
    path[tHi] = (unsigned char)cur;
    const int tLo = (tid == 0) ? 1 : tid * 16;
    for (int t = tHi; t >= tLo; --t) {
      cur = psi[t * 16 + cur];
      path[t - 1] = (unsigned char)cur;
    }
  }
  __syncthreads();

  out[256 + (long)b * 256 + tid] = (float)path[tid];
}

// ------------------------------------------------------------------ launch --
extern "C" void kernel_launch(void* const* d_in, const int* in_sizes, int n_in,
                              void* d_out, int out_size, void* d_ws, size_t ws_size,
                              hipStream_t stream) {
  const float* X     = (const float*)d_in[0];
  const float* W     = (const float*)d_in[1];
  const float* bias  = (const float*)d_in[2];
  const float* trans = (const float*)d_in[3];
  float* out    = (float*)d_out;
  float* featsT = (float*)d_ws;   // 13*65536 floats = 3.4 MB

  feats_kernel<<<256, 256, 0, stream>>>(X, W, bias, featsT);
  viterbi_kernel<<<256, 256, 0, stream>>>(featsT, trans, out);
}